// Round 5
// baseline (390.882 us; speedup 1.0000x reference)
//
#include <hip/hip_runtime.h>
#include <hip/hip_bf16.h>

// BPNN: B=512, N=2048, F=64, T=4, H1=64, H2=32.
// out[b] = sum_n MLP_{t[n]}(x[b,n,:]), MLP = silu(W0 x+b0) -> silu(W1 h+b1) -> w2.h+b2
//
// R5: R4's register-only data path (type-sorted waves, weights in VGPRs,
// layer-1 via the C/D(16x16)==B-frag(16x16x16) layout identity) with higher
// occupancy: NCHUNK 64 -> grid (32,32)=1024 blocks, __launch_bounds__(256,3)
// caps regs at 170 -> 3 blocks/CU (12 waves/CU) for latency hiding.

#define B_ 512
#define N_ 2048
#define F_ 64
#define T_ 4
#define H1_ 64
#define H2_ 32

#define BT 16          // b-tile (MFMA N dim)
#define WAVES 4
#define NCHUNK 64      // n per block

typedef __attribute__((ext_vector_type(8))) short bf16x8;
typedef __attribute__((ext_vector_type(4))) short bf16x4;
typedef __attribute__((ext_vector_type(4))) float f32x4;

#if __has_builtin(__builtin_amdgcn_mfma_f32_16x16x16_bf16)
#define MFMA16(A, Bv, C) __builtin_amdgcn_mfma_f32_16x16x16_bf16((A), (Bv), (C), 0, 0, 0)
#define HAVE_MFMA16 1
#elif __has_builtin(__builtin_amdgcn_mfma_f32_16x16x16bf16_1k)
#define MFMA16(A, Bv, C) __builtin_amdgcn_mfma_f32_16x16x16bf16_1k((A), (Bv), (C), 0, 0, 0)
#define HAVE_MFMA16 1
#else
#define HAVE_MFMA16 0   // fallback: LDS transpose path
#endif

__device__ inline float silu_f(float v) {
    return v * __builtin_amdgcn_rcpf(1.0f + __expf(-v));
}

__device__ inline bf16x8 pack8(float4 a, float4 b) {
    union { __hip_bfloat162 h[4]; bf16x8 v; } u;
    u.h[0] = __float22bfloat162_rn({a.x, a.y});
    u.h[1] = __float22bfloat162_rn({a.z, a.w});
    u.h[2] = __float22bfloat162_rn({b.x, b.y});
    u.h[3] = __float22bfloat162_rn({b.z, b.w});
    return u.v;
}

__device__ inline bf16x4 pack4(float a, float b, float c, float d) {
    union { __hip_bfloat162 h[2]; bf16x4 v; } u;
    u.h[0] = __float22bfloat162_rn({a, b});
    u.h[1] = __float22bfloat162_rn({c, d});
    return u.v;
}

__global__ __launch_bounds__(256, 3) void bpnn_kernel(
    const float* __restrict__ x, const int* __restrict__ an,
    const float* __restrict__ w0, const float* __restrict__ b0,
    const float* __restrict__ w1, const float* __restrict__ b1,
    const float* __restrict__ w2, const float* __restrict__ b2,
    float* __restrict__ out)
{
#if !HAVE_MFMA16
    __shared__ __align__(16) __hip_bfloat16 trb[WAVES][BT][68];
#endif
    __shared__ int sidx[NCHUNK];     // type-sorted n-local indices
    __shared__ int cnt[T_], offs[T_], pos[T_];
    __shared__ float red[BT];

    const int tid  = threadIdx.x;
    const int wave = tid >> 6;
    const int lane = tid & 63;
    const int lr   = lane & 15;      // b-col (B,C) / m-row (A)
    const int q    = lane >> 4;      // quad
    const int b0i  = blockIdx.y * BT;
    const int n0   = blockIdx.x * NCHUNK;
    const int t    = wave;           // this wave's atom type

    // ---- weight fragments for type t: global -> VGPR, once per block ----
    const float* w0t = w0 + t * (H1_ * F_);
    const float* w1t = w1 + t * (H2_ * H1_);
    // layer-0 A-frags (16x16x32): lane (m=lr, k=q*8+j)
    bf16x8 aw0[4][2];
#pragma unroll
    for (int nt = 0; nt < 4; ++nt)
#pragma unroll
        for (int kh = 0; kh < 2; ++kh) {
            const float4* p = reinterpret_cast<const float4*>(
                w0t + (nt * 16 + lr) * F_ + kh * 32 + q * 8);
            aw0[nt][kh] = pack8(p[0], p[1]);
        }
#if HAVE_MFMA16
    // layer-1 A-frags (16x16x16): lane (m=lr, k=q*4+j), one per K-tile nt
    bf16x4 aw1[2][4];
#pragma unroll
    for (int mt = 0; mt < 2; ++mt)
#pragma unroll
        for (int nt = 0; nt < 4; ++nt) {
            float4 v = *reinterpret_cast<const float4*>(
                w1t + (mt * 16 + lr) * H1_ + nt * 16 + q * 4);
            aw1[mt][nt] = pack4(v.x, v.y, v.z, v.w);
        }
#else
    bf16x8 aw1[2][2];
#pragma unroll
    for (int mt = 0; mt < 2; ++mt)
#pragma unroll
        for (int kh = 0; kh < 2; ++kh) {
            const float4* p = reinterpret_cast<const float4*>(
                w1t + (mt * 16 + lr) * H1_ + kh * 32 + q * 8);
            aw1[mt][kh] = pack8(p[0], p[1]);
        }
#endif
    // biases as fp32 MFMA C-initializers (C rows m = q*4+r)
    f32x4 b0v[4], b1v[2], w2v[2];
#pragma unroll
    for (int nt = 0; nt < 4; ++nt)
        b0v[nt] = *reinterpret_cast<const f32x4*>(b0 + t * H1_ + nt * 16 + q * 4);
#pragma unroll
    for (int mt = 0; mt < 2; ++mt) {
        b1v[mt] = *reinterpret_cast<const f32x4*>(b1 + t * H2_ + mt * 16 + q * 4);
        w2v[mt] = *reinterpret_cast<const f32x4*>(w2 + t * H2_ + mt * 16 + q * 4);
    }
    const float b2t = b2[t];

    // ---- counting sort of the block's atoms by type ----
    if (tid < T_)  cnt[tid] = 0;
    if (tid < BT)  red[tid] = 0.0f;
    __syncthreads();
    int myt = 0;
    if (tid < NCHUNK) { myt = an[n0 + tid]; atomicAdd(&cnt[myt], 1); }
    __syncthreads();
    if (tid == 0) {
        int o = 0;
        for (int k = 0; k < T_; ++k) { offs[k] = o; pos[k] = o; o += cnt[k]; }
    }
    __syncthreads();
    if (tid < NCHUNK) { int p = atomicAdd(&pos[myt], 1); sidx[p] = tid; }
    __syncthreads();

    const int beg = offs[t];
    const int num = __builtin_amdgcn_readfirstlane(cnt[t]);

    const float* xb_ = x + (size_t)(b0i + lr) * (N_ * F_) + (size_t)n0 * F_ + q * 8;
#if !HAVE_MFMA16
    __hip_bfloat16* trbw = &trb[wave][lr][0];
#endif

    float esum = 0.f;   // partial energy for b = b0i+lr (this lane's g-slice)

    if (num > 0) {
        int nl = sidx[beg];
        const float4* p0 = reinterpret_cast<const float4*>(xb_ + nl * F_);
        float4 pa = p0[0], pb = p0[1], pc = p0[8], pd = p0[9];

        for (int it = 0; it < num; ++it) {
            bf16x8 xf0 = pack8(pa, pb);
            bf16x8 xf1 = pack8(pc, pd);
            {   // prefetch next iteration's x row
                int ii = (it + 1 < num) ? (it + 1) : it;
                int nn = sidx[beg + ii];
                const float4* pn = reinterpret_cast<const float4*>(xb_ + nn * F_);
                pa = pn[0]; pb = pn[1]; pc = pn[8]; pd = pn[9];
            }

            // ---- layer 0: D0[64h x 16b] = W0_t * x^T + b0 ----
            f32x4 acc[4] = {b0v[0], b0v[1], b0v[2], b0v[3]};
#pragma unroll
            for (int nt = 0; nt < 4; ++nt) {
                acc[nt] = __builtin_amdgcn_mfma_f32_16x16x32_bf16(aw0[nt][0], xf0, acc[nt], 0, 0, 0);
                acc[nt] = __builtin_amdgcn_mfma_f32_16x16x32_bf16(aw0[nt][1], xf1, acc[nt], 0, 0, 0);
            }
            // silu -> bf16x4 per tile; C-layout(16x16) == B-frag(16x16x16):
            // lane holds h = nt*16 + q*4 + r, b = lr -> tile nt is B-frag of K-tile nt
            bf16x4 hb[4];
#pragma unroll
            for (int nt = 0; nt < 4; ++nt)
                hb[nt] = pack4(silu_f(acc[nt][0]), silu_f(acc[nt][1]),
                               silu_f(acc[nt][2]), silu_f(acc[nt][3]));

            // ---- layer 1: D1[32g x 16b] = W1_t * h1 + b1 ----
            f32x4 accB[2] = {b1v[0], b1v[1]};
#if HAVE_MFMA16
#pragma unroll
            for (int mt = 0; mt < 2; ++mt)
#pragma unroll
                for (int nt = 0; nt < 4; ++nt)
                    accB[mt] = MFMA16(aw1[mt][nt], hb[nt], accB[mt]);
#else
#pragma unroll
            for (int nt = 0; nt < 4; ++nt)
                *reinterpret_cast<bf16x4*>(trbw + nt * 16 + q * 4) = hb[nt];
            __builtin_amdgcn_wave_barrier();
            bf16x8 hb0 = *reinterpret_cast<const bf16x8*>(trbw + q * 8);
            bf16x8 hb1 = *reinterpret_cast<const bf16x8*>(trbw + 32 + q * 8);
            __builtin_amdgcn_wave_barrier();
#pragma unroll
            for (int mt = 0; mt < 2; ++mt) {
                accB[mt] = __builtin_amdgcn_mfma_f32_16x16x32_bf16(aw1[mt][0], hb0, accB[mt], 0, 0, 0);
                accB[mt] = __builtin_amdgcn_mfma_f32_16x16x32_bf16(aw1[mt][1], hb1, accB[mt], 0, 0, 0);
            }
#endif
            // ---- layer 2: lane accumulates w2[g]*silu(.) over its 8 g ----
#pragma unroll
            for (int mt = 0; mt < 2; ++mt)
#pragma unroll
                for (int r = 0; r < 4; ++r)
                    esum += silu_f(accB[mt][r]) * w2v[mt][r];
        }
    }

    // reduce esum over the 4 quads holding the same b (lane bits 4-5)
    esum += __shfl_xor(esum, 16);
    esum += __shfl_xor(esum, 32);
    if (q == 0) atomicAdd(&red[lr], esum + (float)num * b2t);
    __syncthreads();
    if (tid < BT) atomicAdd(&out[b0i + tid], red[tid]);
}

extern "C" void kernel_launch(void* const* d_in, const int* in_sizes, int n_in,
                              void* d_out, int out_size, void* d_ws, size_t ws_size,
                              hipStream_t stream) {
    const float* x  = (const float*)d_in[0];
    const int*   an = (const int*)d_in[1];
    const float* w0 = (const float*)d_in[2];
    const float* b0 = (const float*)d_in[3];
    const float* w1 = (const float*)d_in[4];
    const float* b1 = (const float*)d_in[5];
    const float* w2 = (const float*)d_in[6];
    const float* b2 = (const float*)d_in[7];
    float* out = (float*)d_out;

    hipMemsetAsync(out, 0, B_ * sizeof(float), stream);  // out accumulated via atomics
    dim3 grid(N_ / NCHUNK, B_ / BT);                     // (32, 32) = 1024 blocks, ~3/CU
    bpnn_kernel<<<grid, 256, 0, stream>>>(x, an, w0, b0, w1, b1, w2, b2, out);
}

// Round 6
// 383.128 us; speedup vs baseline: 1.0202x; 1.0202x over previous
//
#include <hip/hip_runtime.h>
#include <hip/hip_bf16.h>

// BPNN: B=512, N=2048, F=64, T=4, H1=64, H2=32.
// out[b] = sum_n MLP_{t[n]}(x[b,n,:]), MLP = silu(W0 x+b0) -> silu(W1 h+b1) -> w2.h+b2
//
// FINAL (= R3, best measured 382.9 us): type-sorted waves. Block = 128 n x
// 16 b. Prologue sorts the 128 atom indices by type (LDS counting sort);
// wave w processes exactly the atoms of type w, so its weight A-fragments
// are loop-invariant and live in VGPRs (loaded once per block; 96 KB total
// weights -> L2-hot). LDS ~9.4 KB. MFMA orientation: D = W * x^T.
// Kernel is HBM-bound: x (268 MB) streamed exactly once ~= 43 us floor;
// measured dur_us is dominated by a fixed ~330 us harness restore/poison
// component (1-GiB ws fills at 84% HBM peak visible in rocprof).

#define B_ 512
#define N_ 2048
#define F_ 64
#define T_ 4
#define H1_ 64
#define H2_ 32

#define BT 16          // b-tile (MFMA N dim)
#define WAVES 4
#define NCHUNK 128     // n per block

typedef __attribute__((ext_vector_type(8))) short bf16x8;
typedef __attribute__((ext_vector_type(4))) short bf16x4;
typedef __attribute__((ext_vector_type(4))) float f32x4;

__device__ inline float silu_f(float v) {
    return v * __builtin_amdgcn_rcpf(1.0f + __expf(-v));
}

__device__ inline bf16x8 pack8(float4 a, float4 b) {
    union { __hip_bfloat162 h[4]; bf16x8 v; } u;
    u.h[0] = __float22bfloat162_rn({a.x, a.y});
    u.h[1] = __float22bfloat162_rn({a.z, a.w});
    u.h[2] = __float22bfloat162_rn({b.x, b.y});
    u.h[3] = __float22bfloat162_rn({b.z, b.w});
    return u.v;
}

__device__ inline bf16x4 pack4(float a, float b, float c, float d) {
    union { __hip_bfloat162 h[2]; bf16x4 v; } u;
    u.h[0] = __float22bfloat162_rn({a, b});
    u.h[1] = __float22bfloat162_rn({c, d});
    return u.v;
}

__device__ inline float bf_at(bf16x4 v, int r) {
    union { bf16x4 v; __hip_bfloat16 h[4]; } u; u.v = v;
    return __bfloat162float(u.h[r]);
}

__global__ __launch_bounds__(256, 3) void bpnn_kernel(
    const float* __restrict__ x, const int* __restrict__ an,
    const float* __restrict__ w0, const float* __restrict__ b0,
    const float* __restrict__ w1, const float* __restrict__ b1,
    const float* __restrict__ w2, const float* __restrict__ b2,
    float* __restrict__ out)
{
    __shared__ __align__(16) __hip_bfloat16 trb[WAVES][BT][68]; // 8704 B transpose buf [b][h]
    __shared__ int sidx[NCHUNK];     // type-sorted n-local indices
    __shared__ int cnt[T_], offs[T_], pos[T_];
    __shared__ float red[BT];

    const int tid  = threadIdx.x;
    const int wave = tid >> 6;
    const int lane = tid & 63;
    const int lr   = lane & 15;      // b-col (B,C) / row (A)
    const int q    = lane >> 4;      // quad
    const int b0i  = blockIdx.y * BT;
    const int n0   = blockIdx.x * NCHUNK;
    const int t    = wave;           // this wave's atom type

    // ---- weight fragments for type t: global -> VGPR, once per block ----
    // A-frag lane mapping (m = lane&15, k = quad*8+j): contiguous 8 floats.
    const float* w0t = w0 + t * (H1_ * F_);
    const float* w1t = w1 + t * (H2_ * H1_);
    bf16x8 aw0[4][2], aw1[2][2];
#pragma unroll
    for (int nt = 0; nt < 4; ++nt)
#pragma unroll
        for (int kh = 0; kh < 2; ++kh) {
            const float4* p = reinterpret_cast<const float4*>(
                w0t + (nt * 16 + lr) * F_ + kh * 32 + q * 8);
            aw0[nt][kh] = pack8(p[0], p[1]);
        }
#pragma unroll
    for (int mt = 0; mt < 2; ++mt)
#pragma unroll
        for (int kh = 0; kh < 2; ++kh) {
            const float4* p = reinterpret_cast<const float4*>(
                w1t + (mt * 16 + lr) * H1_ + kh * 32 + q * 8);
            aw1[mt][kh] = pack8(p[0], p[1]);
        }
    bf16x4 b0f[4], b1f[2], w2f[2];
#pragma unroll
    for (int nt = 0; nt < 4; ++nt) {
        float4 v = *reinterpret_cast<const float4*>(b0 + t * H1_ + nt * 16 + q * 4);
        b0f[nt] = pack4(v.x, v.y, v.z, v.w);
    }
#pragma unroll
    for (int mt = 0; mt < 2; ++mt) {
        float4 v = *reinterpret_cast<const float4*>(b1 + t * H2_ + mt * 16 + q * 4);
        b1f[mt] = pack4(v.x, v.y, v.z, v.w);
        float4 u = *reinterpret_cast<const float4*>(w2 + t * H2_ + mt * 16 + q * 4);
        w2f[mt] = pack4(u.x, u.y, u.z, u.w);
    }
    const float b2t = b2[t];

    // ---- counting sort of the block's atoms by type ----
    if (tid < T_)  cnt[tid] = 0;
    if (tid < BT)  red[tid] = 0.0f;
    __syncthreads();
    int myt = 0;
    if (tid < NCHUNK) { myt = an[n0 + tid]; atomicAdd(&cnt[myt], 1); }
    __syncthreads();
    if (tid == 0) {
        int o = 0;
        for (int k = 0; k < T_; ++k) { offs[k] = o; pos[k] = o; o += cnt[k]; }
    }
    __syncthreads();
    if (tid < NCHUNK) { int p = atomicAdd(&pos[myt], 1); sidx[p] = tid; }
    __syncthreads();

    const int beg = offs[t];
    const int num = __builtin_amdgcn_readfirstlane(cnt[t]);

    const float* xb_ = x + (size_t)(b0i + lr) * (N_ * F_) + (size_t)n0 * F_ + q * 8;
    __hip_bfloat16* trbw = &trb[wave][lr][0];

    float esum = 0.f;   // partial energy for b = b0i+lr (this lane's quad k-slice)

    if (num > 0) {
        // prefetch iter 0 (raw floats stay in regs; pack at consume time)
        int nl = sidx[beg];
        const float4* p0 = reinterpret_cast<const float4*>(xb_ + nl * F_);
        float4 pa = p0[0], pb = p0[1], pc = p0[8], pd = p0[9];

        for (int it = 0; it < num; ++it) {
            // consume current, then immediately issue next iteration's loads
            bf16x8 xf0 = pack8(pa, pb);
            bf16x8 xf1 = pack8(pc, pd);
            {
                int ii = (it + 1 < num) ? (it + 1) : it;
                int nn = sidx[beg + ii];
                const float4* pn = reinterpret_cast<const float4*>(xb_ + nn * F_);
                pa = pn[0]; pb = pn[1]; pc = pn[8]; pd = pn[9];
            }

            // ---- layer 0: D0[64h x 16b] = W0_t * x^T ----
            f32x4 acc[4] = {{0,0,0,0},{0,0,0,0},{0,0,0,0},{0,0,0,0}};
#pragma unroll
            for (int nt = 0; nt < 4; ++nt) {
                acc[nt] = __builtin_amdgcn_mfma_f32_16x16x32_bf16(aw0[nt][0], xf0, acc[nt], 0, 0, 0);
                acc[nt] = __builtin_amdgcn_mfma_f32_16x16x32_bf16(aw0[nt][1], xf1, acc[nt], 0, 0, 0);
            }
            // bias + silu; C-layout lane holds h = nt*16 + q*4 + r, b = lr
#pragma unroll
            for (int nt = 0; nt < 4; ++nt) {
                float v0 = silu_f(acc[nt][0] + bf_at(b0f[nt], 0));
                float v1 = silu_f(acc[nt][1] + bf_at(b0f[nt], 1));
                float v2 = silu_f(acc[nt][2] + bf_at(b0f[nt], 2));
                float v3 = silu_f(acc[nt][3] + bf_at(b0f[nt], 3));
                *reinterpret_cast<bf16x4*>(trbw + nt * 16 + q * 4) = pack4(v0, v1, v2, v3);
            }
            __builtin_amdgcn_wave_barrier();  // order LDS write->read (per-wave buffer)

            bf16x8 hb0 = *reinterpret_cast<const bf16x8*>(trbw + q * 8);
            bf16x8 hb1 = *reinterpret_cast<const bf16x8*>(trbw + 32 + q * 8);
            __builtin_amdgcn_wave_barrier();

            // ---- layer 1: D1[32g x 16b] = W1_t * h1 ----
            f32x4 accB[2] = {{0,0,0,0},{0,0,0,0}};
#pragma unroll
            for (int mt = 0; mt < 2; ++mt) {
                accB[mt] = __builtin_amdgcn_mfma_f32_16x16x32_bf16(aw1[mt][0], hb0, accB[mt], 0, 0, 0);
                accB[mt] = __builtin_amdgcn_mfma_f32_16x16x32_bf16(aw1[mt][1], hb1, accB[mt], 0, 0, 0);
            }
            // ---- layer 2: lane accumulates w2[g]*silu(.) over its 8 g ----
#pragma unroll
            for (int mt = 0; mt < 2; ++mt) {
#pragma unroll
                for (int r = 0; r < 4; ++r) {
                    float v = silu_f(accB[mt][r] + bf_at(b1f[mt], r));
                    esum += v * bf_at(w2f[mt], r);
                }
            }
        }
    }

    // reduce esum over the 4 quads holding the same b (lane bits 4-5)
    esum += __shfl_xor(esum, 16);
    esum += __shfl_xor(esum, 32);
    if (q == 0) atomicAdd(&red[lr], esum + (float)num * b2t);
    __syncthreads();
    if (tid < BT) atomicAdd(&out[b0i + tid], red[tid]);
}

extern "C" void kernel_launch(void* const* d_in, const int* in_sizes, int n_in,
                              void* d_out, int out_size, void* d_ws, size_t ws_size,
                              hipStream_t stream) {
    const float* x  = (const float*)d_in[0];
    const int*   an = (const int*)d_in[1];
    const float* w0 = (const float*)d_in[2];
    const float* b0 = (const float*)d_in[3];
    const float* w1 = (const float*)d_in[4];
    const float* b1 = (const float*)d_in[5];
    const float* w2 = (const float*)d_in[6];
    const float* b2 = (const float*)d_in[7];
    float* out = (float*)d_out;

    hipMemsetAsync(out, 0, B_ * sizeof(float), stream);  // out accumulated via atomics
    dim3 grid(N_ / NCHUNK, B_ / BT);                     // (16, 32) = 512 blocks
    bpnn_kernel<<<grid, 256, 0, stream>>>(x, an, w0, b0, w1, b1, w2, b2, out);
}